// Round 17
// baseline (1042.891 us; speedup 1.0000x reference)
//
#include <hip/hip_runtime.h>
#include <cstdint>
#include <cstddef>

#define H_DIM 4096
#define DFF_DIM 16384
#define NROWS 4096  // B*S = 2*2048

typedef unsigned short bf16_t;
typedef __attribute__((ext_vector_type(8))) short bf16x8;
typedef __attribute__((ext_vector_type(4))) float f32x4;
typedef __attribute__((ext_vector_type(4))) unsigned short u16x4;

static __device__ __forceinline__ bf16_t f2bf(float f) {
  union { float f; unsigned int i; } v; v.f = f;
  unsigned int x = v.i;
  return (bf16_t)((x + 0x7fffu + ((x >> 16) & 1u)) >> 16);  // RNE
}

// global -> LDS direct async copy, 16B per lane (wave-uniform base + lane*16).
#define GLDS16(gp, lp)                                                    \
  __builtin_amdgcn_global_load_lds(                                       \
      (__attribute__((address_space(1))) void*)(gp),                      \
      (__attribute__((address_space(3))) void*)(lp), 16, 0, 0)

// ---------------------------------------------------------------------------
// Kernel 1 (merged): role-split grid.
//   bid < NROWS: ln = LN(input + residual + bias) -> bf16 lnb
//   else:        T1 transpose: inter_w fp32 [H,DFF] -> w1t bf16 [DFF,H]
// Both roles are HBM-BW-bound; merging removes a launch boundary and shares
// the HBM pipe. Static LDS = max(tile 16.6KB, sred 32B) -> ~9 blocks/CU.
// ---------------------------------------------------------------------------
__global__ __launch_bounds__(256) void ln_t1_kernel(
    const float* __restrict__ inp, const float* __restrict__ res,
    const float* __restrict__ bias, const float* __restrict__ gamma,
    const float* __restrict__ beta, bf16_t* __restrict__ lnb,
    const float* __restrict__ W, bf16_t* __restrict__ Wt) {
  __shared__ float tile[64][65];
  int bid = blockIdx.x;
  int t = threadIdx.x;

  if (bid < NROWS) {  // ---- LN role ----
    int row = bid;
    const float4* pin = (const float4*)(inp + (size_t)row * H_DIM);
    const float4* pre = (const float4*)(res + (size_t)row * H_DIM);
    const float4* pbi = (const float4*)bias;
    float4 xv[4];
    float s = 0.f, ss = 0.f;
#pragma unroll
    for (int i = 0; i < 4; ++i) {
      int idx = t + i * 256;
      float4 a = pin[idx];
      float4 b = pre[idx];
      float4 c = pbi[idx];
      float4 v;
      v.x = a.x + b.x + c.x;
      v.y = a.y + b.y + c.y;
      v.z = a.z + b.z + c.z;
      v.w = a.w + b.w + c.w;
      xv[i] = v;
      s += v.x + v.y + v.z + v.w;
      ss += v.x * v.x + v.y * v.y + v.z * v.z + v.w * v.w;
    }
#pragma unroll
    for (int off = 32; off > 0; off >>= 1) {
      s += __shfl_xor(s, off);
      ss += __shfl_xor(ss, off);
    }
    float* sred = &tile[0][0];
    int w = t >> 6, l = t & 63;
    if (l == 0) { sred[w] = s; sred[4 + w] = ss; }
    __syncthreads();
    s = sred[0] + sred[1] + sred[2] + sred[3];
    ss = sred[4] + sred[5] + sred[6] + sred[7];
    const float inv = 1.f / (float)H_DIM;
    float mean = s * inv;
    float var = ss * inv - mean * mean;
    float rstd = rsqrtf(var + 1e-5f);
    const float4* pg = (const float4*)gamma;
    const float4* pb = (const float4*)beta;
#pragma unroll
    for (int i = 0; i < 4; ++i) {
      int idx = t + i * 256;
      float4 g = pg[idx];
      float4 bb = pb[idx];
      float4 v = xv[i];
      u16x4 o;
      o.x = f2bf((v.x - mean) * rstd * g.x + bb.x);
      o.y = f2bf((v.y - mean) * rstd * g.y + bb.y);
      o.z = f2bf((v.z - mean) * rstd * g.z + bb.z);
      o.w = f2bf((v.w - mean) * rstd * g.w + bb.w);
      *(u16x4*)(lnb + (size_t)row * H_DIM + (size_t)idx * 4) = o;
    }
    return;
  }

  // ---- T1 transpose role: W [H_DIM, DFF_DIM] -> Wt [DFF_DIM, H_DIM] ----
  int tb = bid - NROWS;              // 0 .. (H/64)*(DFF/64)-1
  int nb = DFF_DIM >> 6;             // 256
  int bk = tb / nb;
  int bn = tb - bk * nb;
  int r = t >> 4;
  int c4 = (t & 15) << 2;
#pragma unroll
  for (int p = 0; p < 4; ++p) {
    int row = r + p * 16;
    float4 v =
        *(const float4*)(W + (size_t)(bk * 64 + row) * DFF_DIM + bn * 64 + c4);
    tile[row][c4 + 0] = v.x;
    tile[row][c4 + 1] = v.y;
    tile[row][c4 + 2] = v.z;
    tile[row][c4 + 3] = v.w;
  }
  __syncthreads();
#pragma unroll
  for (int p = 0; p < 4; ++p) {
    int nn = r + p * 16;
    u16x4 o;
    o.x = f2bf(tile[c4 + 0][nn]);
    o.y = f2bf(tile[c4 + 1][nn]);
    o.z = f2bf(tile[c4 + 2][nn]);
    o.w = f2bf(tile[c4 + 3][nn]);
    *(u16x4*)(Wt + (size_t)(bn * 64 + nn) * H_DIM + bk * 64 + c4) = o;
  }
}

// ---------------------------------------------------------------------------
// Kernel 3: 256x256 8-phase bf16 GEMM (C = A * Bt^T), fp32 acc. K-loop = R10
// (read-ahead-one-phase in-place, vmcnt(6)@P4/P8, octet XOR swizzle, R5
// chunk map) — byte-identical to R16 (best passing). R17 delta: fused-T2
// tail uses CONTIGUOUS tile mapping tau = bid*16 + j (one 64-row x 1024-col
// panel per block, same bk, 16 consecutive bn) instead of stride-1024 —
// per-row reads become 4KB-sequential across the j-loop; better L2/fetch
// granularity on the tail's 384 MB. Loads stay pipelined one tile ahead
// (16-VGPR live range confined to the tail).
// EPI 0: out_bf16 = gelu_tanh(C + eb1[n]);  EPI 1: out_f32 = C + eb1 + eb2
// + add1 + add2.
// ---------------------------------------------------------------------------
#define QMFMA_H(AQ, BQ, MILO, NJLO, K5)                                     \
  __builtin_amdgcn_s_setprio(1);                                            \
  _Pragma("unroll") for (int i5 = 0; i5 < 4; ++i5)                          \
  _Pragma("unroll") for (int j5 = 0; j5 < 2; ++j5)                          \
    acc[MILO + i5][NJLO + j5] = __builtin_amdgcn_mfma_f32_16x16x32_bf16(    \
        AQ[i5 * 2 + K5], BQ[j5 * 2 + K5], acc[MILO + i5][NJLO + j5], 0, 0, 0); \
  __builtin_amdgcn_s_setprio(0);

#define BAR __builtin_amdgcn_s_barrier()
#define VM6 asm volatile("s_waitcnt vmcnt(6)" ::: "memory")

template <int EPI>
__global__ __launch_bounds__(512, 2) void gemm8p_kernel(
    const bf16_t* __restrict__ A, const bf16_t* __restrict__ Bt,
    int M, int N, int K,
    const float* __restrict__ eb1, const float* __restrict__ eb2,
    const float* __restrict__ add1, const float* __restrict__ add2,
    bf16_t* __restrict__ outb, float* __restrict__ outf,
    const float* __restrict__ tsrc, bf16_t* __restrict__ tdst) {
  __shared__ char lds[131072];  // A: [buf][half] 4 x 16KB @0; B @65536

  const int t = threadIdx.x;
  const int l = t & 63;
  const int wid = t >> 6;
  const int wr = wid >> 2;  // 0..1
  const int wc = wid & 3;   // 0..3

  // Block -> tile: XCD chunk swizzle, 32-wg chunks shaped 8(tm) x 4(tn).
  int nwg = gridDim.x;
  int bid = blockIdx.x;
  int wg = (bid & 7) * (nwg >> 3) + (bid >> 3);
  int ntm = M >> 8;
  int chunk = wg >> 5, s5 = wg & 31;
  int cmn = ntm >> 3;
  int cm = chunk % cmn, cn = chunk / cmn;
  int tm = cm * 8 + (s5 & 7);
  int tn = cn * 4 + (s5 >> 3);
  size_t m0 = (size_t)tm * 256, n0 = (size_t)tn * 256;

  f32x4 acc[8][4];
#pragma unroll
  for (int i = 0; i < 8; ++i)
#pragma unroll
    for (int j = 0; j < 4; ++j) acc[i][j] = {0.f, 0.f, 0.f, 0.f};

  // ---- staging thread map: half-tile = [128 rows][64 k] = 1024 x 16B.
  const int rh = t >> 3;
  const int sl = t & 7;
  const int oc = sl ^ ((rh >> 1) & 7);
  const bf16_t* sA0 = A + (m0 + rh) * (size_t)K + oc * 8;
  const bf16_t* sA1 = A + (m0 + rh + 64) * (size_t)K + oc * 8;
  const bf16_t* sB0 = Bt + (n0 + rh) * (size_t)K + oc * 8;
  const bf16_t* sB1 = Bt + (n0 + rh + 64) * (size_t)K + oc * 8;

  auto stA = [&](int b, int h, int T) {
    GLDS16(sA0 + (size_t)h * 128 * K + (size_t)T * 64,
           lds + b * 32768 + h * 16384 + t * 16);
    GLDS16(sA1 + (size_t)h * 128 * K + (size_t)T * 64,
           lds + b * 32768 + h * 16384 + (t + 512) * 16);
  };
  auto stB = [&](int b, int h, int T) {
    GLDS16(sB0 + (size_t)h * 128 * K + (size_t)T * 64,
           lds + 65536 + b * 32768 + h * 16384 + t * 16);
    GLDS16(sB1 + (size_t)h * 128 * K + (size_t)T * 64,
           lds + 65536 + b * 32768 + h * 16384 + (t + 512) * 16);
  };

  // ---- fragment read offsets (within operand region; +32768 for buf1).
  int offA[8][2], offB[4][2];
#pragma unroll
  for (int mi = 0; mi < 8; ++mi) {
    int h = mi >> 2;
    int lr = (mi & 3) * 32 + wr * 16 + (l & 15);
#pragma unroll
    for (int ks = 0; ks < 2; ++ks) {
      int o = ks * 4 + (l >> 4);
      offA[mi][ks] = h * 16384 + lr * 128 + ((o ^ ((lr >> 1) & 7)) << 4);
    }
  }
#pragma unroll
  for (int nj = 0; nj < 4; ++nj) {
    int h = nj >> 1;
    int lc = (nj & 1) * 64 + wc * 16 + (l & 15);
#pragma unroll
    for (int ks = 0; ks < 2; ++ks) {
      int o = ks * 4 + (l >> 4);
      offB[nj][ks] = 65536 + h * 16384 + lc * 128 + ((o ^ ((lc >> 1) & 7)) << 4);
    }
  }

  auto rd8 = [&](int off) -> bf16x8 {
    return *(const bf16x8*)(const void*)(lds + off);
  };

  const int NT = K >> 6;   // K-tiles of 64
  const int NI = NT >> 1;  // iterations (2 tiles each)

  // ---- prologue: tile0 (buf0) + 3 halves of tile1 (buf1) = 14 loads.
  stB(0, 0, 0); stA(0, 0, 0); stB(0, 1, 0); stA(0, 1, 0);
  stB(1, 0, 1); stA(1, 0, 1); stB(1, 1, 1);
  VM6;
  BAR;

  // Prime P1 operands: buf0 A-h0 (8) + B-h0 (4). Exposed once.
  bf16x8 aQ[8], bQ0[4], bQ1[4];
#pragma unroll
  for (int i = 0; i < 4; ++i)
#pragma unroll
    for (int ks = 0; ks < 2; ++ks) aQ[i * 2 + ks] = rd8(offA[i][ks]);
#pragma unroll
  for (int j = 0; j < 2; ++j)
#pragma unroll
    for (int ks = 0; ks < 2; ++ks) bQ0[j * 2 + ks] = rd8(offB[j][ks]);

  for (int it = 0; it < NI; ++it) {
    const int Tb = 2 * it + 1;
    int Sa = 2 * it + 2; if (Sa >= NT) Sa = NT - 1;  // tail: dead prefetch
    int Sb = 2 * it + 3; if (Sb >= NT) Sb = NT - 1;

    // ========== tile Ta = 2it (buf0) ==========
    // P1: MFMA A-h0 x B-h0 (0,0); mid-reads: bQ1 <- buf0 B-h1 (for P2).
    stA(1, 1, Tb);
    BAR;
    QMFMA_H(aQ, bQ0, 0, 0, 0)
    bQ1[0] = rd8(offB[2][0]); bQ1[2] = rd8(offB[3][0]);
    QMFMA_H(aQ, bQ0, 0, 0, 1)
    bQ1[1] = rd8(offB[2][1]); bQ1[3] = rd8(offB[3][1]);
    BAR;
    // P2: MFMA A-h0 x B-h1 (0,2); mid-reads: aQ <- buf0 A-h1 (in place).
    stB(0, 0, Sa);
    BAR;
    QMFMA_H(aQ, bQ1, 0, 2, 0)
    aQ[0] = rd8(offA[4][0]); aQ[2] = rd8(offA[5][0]);
    aQ[4] = rd8(offA[6][0]); aQ[6] = rd8(offA[7][0]);
    QMFMA_H(aQ, bQ1, 0, 2, 1)
    aQ[1] = rd8(offA[4][1]); aQ[3] = rd8(offA[5][1]);
    aQ[5] = rd8(offA[6][1]); aQ[7] = rd8(offA[7][1]);
    BAR;
    // P3: MFMA A-h1 x B-h1 (4,2); no reads.
    stA(0, 0, Sa);
    BAR;
    QMFMA_H(aQ, bQ1, 4, 2, 0)
    QMFMA_H(aQ, bQ1, 4, 2, 1)
    BAR;
    // P4: MFMA A-h1 x B-h0 (4,0); VM6 validates buf1 (tile Tb); mid-reads:
    // bQ0/aQ <- buf1 h0 (for P5), in place after each k-half retires.
    stB(0, 1, Sa);
    VM6;
    BAR;
    QMFMA_H(aQ, bQ0, 4, 0, 0)
    bQ0[0] = rd8(32768 + offB[0][0]); bQ0[2] = rd8(32768 + offB[1][0]);
    aQ[0] = rd8(32768 + offA[0][0]); aQ[2] = rd8(32768 + offA[1][0]);
    aQ[4] = rd8(32768 + offA[2][0]); aQ[6] = rd8(32768 + offA[3][0]);
    QMFMA_H(aQ, bQ0, 4, 0, 1)
    bQ0[1] = rd8(32768 + offB[0][1]); bQ0[3] = rd8(32768 + offB[1][1]);
    aQ[1] = rd8(32768 + offA[0][1]); aQ[3] = rd8(32768 + offA[1][1]);
    aQ[5] = rd8(32768 + offA[2][1]); aQ[7] = rd8(32768 + offA[3][1]);
    BAR;

    // ========== tile Tb = 2it+1 (buf1) ==========
    // P5: MFMA A-h0 x B-h0; mid-reads: bQ1 <- buf1 B-h1.
    stA(0, 1, Sa);
    BAR;
    QMFMA_H(aQ, bQ0, 0, 0, 0)
    bQ1[0] = rd8(32768 + offB[2][0]); bQ1[2] = rd8(32768 + offB[3][0]);
    QMFMA_H(aQ, bQ0, 0, 0, 1)
    bQ1[1] = rd8(32768 + offB[2][1]); bQ1[3] = rd8(32768 + offB[3][1]);
    BAR;
    // P6: MFMA A-h0 x B-h1; mid-reads: aQ <- buf1 A-h1.
    stB(1, 0, Sb);
    BAR;
    QMFMA_H(aQ, bQ1, 0, 2, 0)
    aQ[0] = rd8(32768 + offA[4][0]); aQ[2] = rd8(32768 + offA[5][0]);
    aQ[4] = rd8(32768 + offA[6][0]); aQ[6] = rd8(32768 + offA[7][0]);
    QMFMA_H(aQ, bQ1, 0, 2, 1)
    aQ[1] = rd8(32768 + offA[4][1]); aQ[3] = rd8(32768 + offA[5][1]);
    aQ[5] = rd8(32768 + offA[6][1]); aQ[7] = rd8(32768 + offA[7][1]);
    BAR;
    // P7: MFMA A-h1 x B-h1; no reads.
    stA(1, 0, Sb);
    BAR;
    QMFMA_H(aQ, bQ1, 4, 2, 0)
    QMFMA_H(aQ, bQ1, 4, 2, 1)
    BAR;
    // P8: MFMA A-h1 x B-h0; VM6 validates buf0 (tile Sa); mid-reads:
    // bQ0/aQ <- buf0 h0 (for next-iter P1).
    stB(1, 1, Sb);
    VM6;
    BAR;
    QMFMA_H(aQ, bQ0, 4, 0, 0)
    bQ0[0] = rd8(offB[0][0]); bQ0[2] = rd8(offB[1][0]);
    aQ[0] = rd8(offA[0][0]); aQ[2] = rd8(offA[1][0]);
    aQ[4] = rd8(offA[2][0]); aQ[6] = rd8(offA[3][0]);
    QMFMA_H(aQ, bQ0, 4, 0, 1)
    bQ0[1] = rd8(offB[0][1]); bQ0[3] = rd8(offB[1][1]);
    aQ[1] = rd8(offA[0][1]); aQ[3] = rd8(offA[1][1]);
    aQ[5] = rd8(offA[2][1]); aQ[7] = rd8(offA[3][1]);
    BAR;
  }
  asm volatile("s_waitcnt vmcnt(0)" ::: "memory");

  // Epilogue. Interleaved mapping: row = m0 + (mi*2+wr)*16 + (l>>4)*4 + i2,
  // col = n0 + (nj*4+wc)*16 + (l&15).
  int lr4 = (l >> 4) * 4;
  int lc = l & 15;
#pragma unroll
  for (int mi = 0; mi < 8; ++mi) {
#pragma unroll
    for (int i2 = 0; i2 < 4; ++i2) {
      int rrow = (int)m0 + (mi * 2 + wr) * 16 + lr4 + i2;
      size_t base = (size_t)rrow * N;
#pragma unroll
      for (int nj = 0; nj < 4; ++nj) {
        int col = (int)n0 + (nj * 4 + wc) * 16 + lc;
        float v = acc[mi][nj][i2];
        if (EPI == 0) {
          float x = v + eb1[col];
          float u = 0.7978845608028654f * (x + 0.044715f * x * x * x);
          float th = 1.f - 2.f / (__expf(2.f * u) + 1.f);  // tanh(u)
          outb[base + col] = f2bf(0.5f * x * (1.f + th));
        } else {
          outf[base + col] =
              v + eb1[col] + eb2[col] + add1[base + col] + add2[base + col];
        }
      }
    }
  }

  // ---- post-epilogue fused-T2 tail (EPI==0): LDS transpose + bf16 store.
  // CONTIGUOUS mapping: tau = bid*16 + j -> one 64-row x 1024-col source
  // panel per block (same bk for all 16 tiles; bn consecutive). Loads
  // pipelined one tile ahead (16-VGPR live range confined to the tail).
  // One barrier/tile: W_{j+1} targets the other buffer; W_{j+2} vs R_j is
  // separated by sync_{j+1}.
  if (EPI == 0) {
    __syncthreads();  // all waves done with K-loop LDS
    float (*tl0)[65] = (float (*)[65])(void*)lds;
    float (*tl1)[65] = (float (*)[65])(void*)(lds + 16640);
    const int trr = t >> 3;        // 0..63
    const int trc = (t & 7) * 8;   // 0,8,...,56
    const size_t srcoff = (size_t)trr * H_DIM + trc;
    const int tau0 = bid * 16;
    // preload tile 0 into the even-parity registers
    const float* s0 =
        tsrc + (size_t)(tau0 >> 6) * 64 * H_DIM + (tau0 & 63) * 64 + srcoff;
    float4 pa0 = *(const float4*)s0;
    float4 pa1 = *(const float4*)(s0 + 4);
    float4 pb0 = {0.f, 0.f, 0.f, 0.f}, pb1 = {0.f, 0.f, 0.f, 0.f};
#pragma unroll
    for (int j = 0; j < 16; ++j) {
      float (*cur)[65] = (j & 1) ? tl1 : tl0;
      float4 q0 = (j & 1) ? pb0 : pa0;
      float4 q1 = (j & 1) ? pb1 : pa1;
      cur[trr][trc + 0] = q0.x; cur[trr][trc + 1] = q0.y;
      cur[trr][trc + 2] = q0.z; cur[trr][trc + 3] = q0.w;
      cur[trr][trc + 4] = q1.x; cur[trr][trc + 5] = q1.y;
      cur[trr][trc + 6] = q1.z; cur[trr][trc + 7] = q1.w;
      if (j < 15) {  // issue next tile's loads; consumed next iteration
        int tau2 = tau0 + j + 1;
        const float* s2 =
            tsrc + (size_t)(tau2 >> 6) * 64 * H_DIM + (tau2 & 63) * 64 + srcoff;
        if (j & 1) {
          pa0 = *(const float4*)s2; pa1 = *(const float4*)(s2 + 4);
        } else {
          pb0 = *(const float4*)s2; pb1 = *(const float4*)(s2 + 4);
        }
      }
      __syncthreads();
      int tau = tau0 + j;
      int bk = tau >> 6, bn = tau & 63;
      u16x4 o0, o1;
      o0.x = f2bf(cur[trc + 0][trr]); o0.y = f2bf(cur[trc + 1][trr]);
      o0.z = f2bf(cur[trc + 2][trr]); o0.w = f2bf(cur[trc + 3][trr]);
      o1.x = f2bf(cur[trc + 4][trr]); o1.y = f2bf(cur[trc + 5][trr]);
      o1.z = f2bf(cur[trc + 6][trr]); o1.w = f2bf(cur[trc + 7][trr]);
      bf16_t* dst = tdst + (size_t)(bn * 64 + trr) * DFF_DIM + bk * 64 + trc;
      *(u16x4*)dst = o0;
      *(u16x4*)(dst + 4) = o1;
    }
  }
}

// ---------------------------------------------------------------------------
extern "C" void kernel_launch(void* const* d_in, const int* in_sizes, int n_in,
                              void* d_out, int out_size, void* d_ws,
                              size_t ws_size, hipStream_t stream) {
  const float* input = (const float*)d_in[0];
  const float* residual = (const float*)d_in[1];
  const float* bias = (const float*)d_in[3];
  const float* attn_nw = (const float*)d_in[4];
  const float* attn_nb = (const float*)d_in[5];
  const float* inter_w = (const float*)d_in[6];   // [H, DFF]
  const float* inter_b = (const float*)d_in[7];   // [DFF]
  const float* output_w = (const float*)d_in[8];  // [DFF, H]
  const float* output_b = (const float*)d_in[9];  // [H]
  float* out = (float*)d_out;

  char* ws = (char*)d_ws;
  bf16_t* lnb = (bf16_t*)ws;
  bf16_t* w1t = (bf16_t*)(ws + (size_t)NROWS * H_DIM * 2);
  bf16_t* w2t = (bf16_t*)(ws + (size_t)NROWS * H_DIM * 2 +
                          (size_t)H_DIM * DFF_DIM * 2);
  bf16_t* inter = (bf16_t*)(ws + (size_t)NROWS * H_DIM * 2 +
                            2 * (size_t)H_DIM * DFF_DIM * 2);

  // Merged LN + T1 (both HBM-BW-bound; one launch).
  ln_t1_kernel<<<NROWS + (H_DIM / 64) * (DFF_DIM / 64), 256, 0, stream>>>(
      input, residual, bias, attn_nw, attn_nb, lnb, inter_w, w1t);
  // GEMM1 with fused T2 (output_w -> w2t): pipelined, contiguous-panel tail.
  gemm8p_kernel<0><<<(NROWS / 256) * (DFF_DIM / 256), 512, 0, stream>>>(
      lnb, w1t, NROWS, DFF_DIM, H_DIM, inter_b, nullptr, nullptr, nullptr,
      inter, nullptr, output_w, w2t);
  gemm8p_kernel<1><<<(NROWS / 256) * (H_DIM / 256), 512, 0, stream>>>(
      inter, w2t, NROWS, H_DIM, DFF_DIM, bias, output_b, residual, input,
      nullptr, out, nullptr, nullptr);
}

// Round 18
// 1035.336 us; speedup vs baseline: 1.0073x; 1.0073x over previous
//
#include <hip/hip_runtime.h>
#include <cstdint>
#include <cstddef>

#define H_DIM 4096
#define DFF_DIM 16384
#define NROWS 4096  // B*S = 2*2048

typedef unsigned short bf16_t;
typedef __attribute__((ext_vector_type(8))) short bf16x8;
typedef __attribute__((ext_vector_type(4))) float f32x4;
typedef __attribute__((ext_vector_type(4))) unsigned short u16x4;

static __device__ __forceinline__ bf16_t f2bf(float f) {
  union { float f; unsigned int i; } v; v.f = f;
  unsigned int x = v.i;
  return (bf16_t)((x + 0x7fffu + ((x >> 16) & 1u)) >> 16);  // RNE
}

// global -> LDS direct async copy, 16B per lane (wave-uniform base + lane*16).
#define GLDS16(gp, lp)                                                    \
  __builtin_amdgcn_global_load_lds(                                       \
      (__attribute__((address_space(1))) void*)(gp),                      \
      (__attribute__((address_space(3))) void*)(lp), 16, 0, 0)

// ---------------------------------------------------------------------------
// Kernel 1: ln_in = input + residual + bias; LN(ln_in, gamma, beta) -> bf16
// ---------------------------------------------------------------------------
__global__ __launch_bounds__(256) void fused_ln_kernel(
    const float* __restrict__ inp, const float* __restrict__ res,
    const float* __restrict__ bias, const float* __restrict__ gamma,
    const float* __restrict__ beta, bf16_t* __restrict__ out) {
  int row = blockIdx.x;
  int t = threadIdx.x;
  const float4* pin = (const float4*)(inp + (size_t)row * H_DIM);
  const float4* pre = (const float4*)(res + (size_t)row * H_DIM);
  const float4* pbi = (const float4*)bias;
  float4 xv[4];
  float s = 0.f, ss = 0.f;
#pragma unroll
  for (int i = 0; i < 4; ++i) {
    int idx = t + i * 256;
    float4 a = pin[idx];
    float4 b = pre[idx];
    float4 c = pbi[idx];
    float4 v;
    v.x = a.x + b.x + c.x;
    v.y = a.y + b.y + c.y;
    v.z = a.z + b.z + c.z;
    v.w = a.w + b.w + c.w;
    xv[i] = v;
    s += v.x + v.y + v.z + v.w;
    ss += v.x * v.x + v.y * v.y + v.z * v.z + v.w * v.w;
  }
#pragma unroll
  for (int off = 32; off > 0; off >>= 1) {
    s += __shfl_xor(s, off);
    ss += __shfl_xor(ss, off);
  }
  __shared__ float sred[8];
  int w = t >> 6, l = t & 63;
  if (l == 0) { sred[w] = s; sred[4 + w] = ss; }
  __syncthreads();
  s = sred[0] + sred[1] + sred[2] + sred[3];
  ss = sred[4] + sred[5] + sred[6] + sred[7];
  const float inv = 1.f / (float)H_DIM;
  float mean = s * inv;
  float var = ss * inv - mean * mean;
  float rstd = rsqrtf(var + 1e-5f);
  const float4* pg = (const float4*)gamma;
  const float4* pb = (const float4*)beta;
#pragma unroll
  for (int i = 0; i < 4; ++i) {
    int idx = t + i * 256;
    float4 g = pg[idx];
    float4 bb = pb[idx];
    float4 v = xv[i];
    u16x4 o;
    o.x = f2bf((v.x - mean) * rstd * g.x + bb.x);
    o.y = f2bf((v.y - mean) * rstd * g.y + bb.y);
    o.z = f2bf((v.z - mean) * rstd * g.z + bb.z);
    o.w = f2bf((v.w - mean) * rstd * g.w + bb.w);
    *(u16x4*)(out + (size_t)row * H_DIM + (size_t)idx * 4) = o;
  }
}

// ---------------------------------------------------------------------------
// Kernel 2: W fp32 [K,N] -> Wt bf16 [N,K] (transpose + convert). Used for T1
// only; T2 is folded into gemm8p_kernel<0>.
// ---------------------------------------------------------------------------
__global__ __launch_bounds__(256) void transpose_cvt_kernel(
    const float* __restrict__ W, bf16_t* __restrict__ Wt, int K, int N) {
  __shared__ float tile[64][65];
  int nb = N >> 6;
  int bk = blockIdx.x / nb;
  int bn = blockIdx.x - bk * nb;
  int t = threadIdx.x;
  int r = t >> 4;
  int c4 = (t & 15) << 2;
#pragma unroll
  for (int p = 0; p < 4; ++p) {
    int row = r + p * 16;
    float4 v = *(const float4*)(W + (size_t)(bk * 64 + row) * N + bn * 64 + c4);
    tile[row][c4 + 0] = v.x;
    tile[row][c4 + 1] = v.y;
    tile[row][c4 + 2] = v.z;
    tile[row][c4 + 3] = v.w;
  }
  __syncthreads();
#pragma unroll
  for (int p = 0; p < 4; ++p) {
    int nn = r + p * 16;
    u16x4 o;
    o.x = f2bf(tile[c4 + 0][nn]);
    o.y = f2bf(tile[c4 + 1][nn]);
    o.z = f2bf(tile[c4 + 2][nn]);
    o.w = f2bf(tile[c4 + 3][nn]);
    *(u16x4*)(Wt + (size_t)(bn * 64 + nn) * K + bk * 64 + c4) = o;
  }
}

// ---------------------------------------------------------------------------
// Kernel 3: 256x256 8-phase bf16 GEMM (C = A * Bt^T), fp32 acc. K-loop = R10
// (read-ahead-one-phase in-place, vmcnt(6)@P4/P8, octet XOR swizzle, R5
// chunk map). Fused-T2 tail (EPI==0) pipelines its HBM loads ONE TILE AHEAD
// with a 16-VGPR live range confined to the tail (acc dead). One barrier per
// tile (W_{j+1} -> other buffer; W_{j+2} vs R_j separated by sync_{j+1}).
// This is the R16 configuration — measured best (1039.7 us total).
// EPI 0: out_bf16 = gelu_tanh(C + eb1[n]);  EPI 1: out_f32 = C + eb1 + eb2
// + add1 + add2.
// ---------------------------------------------------------------------------
#define QMFMA_H(AQ, BQ, MILO, NJLO, K5)                                     \
  __builtin_amdgcn_s_setprio(1);                                            \
  _Pragma("unroll") for (int i5 = 0; i5 < 4; ++i5)                          \
  _Pragma("unroll") for (int j5 = 0; j5 < 2; ++j5)                          \
    acc[MILO + i5][NJLO + j5] = __builtin_amdgcn_mfma_f32_16x16x32_bf16(    \
        AQ[i5 * 2 + K5], BQ[j5 * 2 + K5], acc[MILO + i5][NJLO + j5], 0, 0, 0); \
  __builtin_amdgcn_s_setprio(0);

#define BAR __builtin_amdgcn_s_barrier()
#define VM6 asm volatile("s_waitcnt vmcnt(6)" ::: "memory")

template <int EPI>
__global__ __launch_bounds__(512, 2) void gemm8p_kernel(
    const bf16_t* __restrict__ A, const bf16_t* __restrict__ Bt,
    int M, int N, int K,
    const float* __restrict__ eb1, const float* __restrict__ eb2,
    const float* __restrict__ add1, const float* __restrict__ add2,
    bf16_t* __restrict__ outb, float* __restrict__ outf,
    const float* __restrict__ tsrc, bf16_t* __restrict__ tdst) {
  __shared__ char lds[131072];  // A: [buf][half] 4 x 16KB @0; B @65536

  const int t = threadIdx.x;
  const int l = t & 63;
  const int wid = t >> 6;
  const int wr = wid >> 2;  // 0..1
  const int wc = wid & 3;   // 0..3

  // Block -> tile: XCD chunk swizzle, 32-wg chunks shaped 8(tm) x 4(tn).
  int nwg = gridDim.x;
  int bid = blockIdx.x;
  int wg = (bid & 7) * (nwg >> 3) + (bid >> 3);
  int ntm = M >> 8;
  int chunk = wg >> 5, s5 = wg & 31;
  int cmn = ntm >> 3;
  int cm = chunk % cmn, cn = chunk / cmn;
  int tm = cm * 8 + (s5 & 7);
  int tn = cn * 4 + (s5 >> 3);
  size_t m0 = (size_t)tm * 256, n0 = (size_t)tn * 256;

  f32x4 acc[8][4];
#pragma unroll
  for (int i = 0; i < 8; ++i)
#pragma unroll
    for (int j = 0; j < 4; ++j) acc[i][j] = {0.f, 0.f, 0.f, 0.f};

  // ---- staging thread map: half-tile = [128 rows][64 k] = 1024 x 16B.
  const int rh = t >> 3;
  const int sl = t & 7;
  const int oc = sl ^ ((rh >> 1) & 7);
  const bf16_t* sA0 = A + (m0 + rh) * (size_t)K + oc * 8;
  const bf16_t* sA1 = A + (m0 + rh + 64) * (size_t)K + oc * 8;
  const bf16_t* sB0 = Bt + (n0 + rh) * (size_t)K + oc * 8;
  const bf16_t* sB1 = Bt + (n0 + rh + 64) * (size_t)K + oc * 8;

  auto stA = [&](int b, int h, int T) {
    GLDS16(sA0 + (size_t)h * 128 * K + (size_t)T * 64,
           lds + b * 32768 + h * 16384 + t * 16);
    GLDS16(sA1 + (size_t)h * 128 * K + (size_t)T * 64,
           lds + b * 32768 + h * 16384 + (t + 512) * 16);
  };
  auto stB = [&](int b, int h, int T) {
    GLDS16(sB0 + (size_t)h * 128 * K + (size_t)T * 64,
           lds + 65536 + b * 32768 + h * 16384 + t * 16);
    GLDS16(sB1 + (size_t)h * 128 * K + (size_t)T * 64,
           lds + 65536 + b * 32768 + h * 16384 + (t + 512) * 16);
  };

  // ---- fragment read offsets (within operand region; +32768 for buf1).
  int offA[8][2], offB[4][2];
#pragma unroll
  for (int mi = 0; mi < 8; ++mi) {
    int h = mi >> 2;
    int lr = (mi & 3) * 32 + wr * 16 + (l & 15);
#pragma unroll
    for (int ks = 0; ks < 2; ++ks) {
      int o = ks * 4 + (l >> 4);
      offA[mi][ks] = h * 16384 + lr * 128 + ((o ^ ((lr >> 1) & 7)) << 4);
    }
  }
#pragma unroll
  for (int nj = 0; nj < 4; ++nj) {
    int h = nj >> 1;
    int lc = (nj & 1) * 64 + wc * 16 + (l & 15);
#pragma unroll
    for (int ks = 0; ks < 2; ++ks) {
      int o = ks * 4 + (l >> 4);
      offB[nj][ks] = 65536 + h * 16384 + lc * 128 + ((o ^ ((lc >> 1) & 7)) << 4);
    }
  }

  auto rd8 = [&](int off) -> bf16x8 {
    return *(const bf16x8*)(const void*)(lds + off);
  };

  const int NT = K >> 6;   // K-tiles of 64
  const int NI = NT >> 1;  // iterations (2 tiles each)

  // ---- prologue: tile0 (buf0) + 3 halves of tile1 (buf1) = 14 loads.
  stB(0, 0, 0); stA(0, 0, 0); stB(0, 1, 0); stA(0, 1, 0);
  stB(1, 0, 1); stA(1, 0, 1); stB(1, 1, 1);
  VM6;
  BAR;

  // Prime P1 operands: buf0 A-h0 (8) + B-h0 (4). Exposed once.
  bf16x8 aQ[8], bQ0[4], bQ1[4];
#pragma unroll
  for (int i = 0; i < 4; ++i)
#pragma unroll
    for (int ks = 0; ks < 2; ++ks) aQ[i * 2 + ks] = rd8(offA[i][ks]);
#pragma unroll
  for (int j = 0; j < 2; ++j)
#pragma unroll
    for (int ks = 0; ks < 2; ++ks) bQ0[j * 2 + ks] = rd8(offB[j][ks]);

  for (int it = 0; it < NI; ++it) {
    const int Tb = 2 * it + 1;
    int Sa = 2 * it + 2; if (Sa >= NT) Sa = NT - 1;  // tail: dead prefetch
    int Sb = 2 * it + 3; if (Sb >= NT) Sb = NT - 1;

    // ========== tile Ta = 2it (buf0) ==========
    // P1: MFMA A-h0 x B-h0 (0,0); mid-reads: bQ1 <- buf0 B-h1 (for P2).
    stA(1, 1, Tb);
    BAR;
    QMFMA_H(aQ, bQ0, 0, 0, 0)
    bQ1[0] = rd8(offB[2][0]); bQ1[2] = rd8(offB[3][0]);
    QMFMA_H(aQ, bQ0, 0, 0, 1)
    bQ1[1] = rd8(offB[2][1]); bQ1[3] = rd8(offB[3][1]);
    BAR;
    // P2: MFMA A-h0 x B-h1 (0,2); mid-reads: aQ <- buf0 A-h1 (in place).
    stB(0, 0, Sa);
    BAR;
    QMFMA_H(aQ, bQ1, 0, 2, 0)
    aQ[0] = rd8(offA[4][0]); aQ[2] = rd8(offA[5][0]);
    aQ[4] = rd8(offA[6][0]); aQ[6] = rd8(offA[7][0]);
    QMFMA_H(aQ, bQ1, 0, 2, 1)
    aQ[1] = rd8(offA[4][1]); aQ[3] = rd8(offA[5][1]);
    aQ[5] = rd8(offA[6][1]); aQ[7] = rd8(offA[7][1]);
    BAR;
    // P3: MFMA A-h1 x B-h1 (4,2); no reads.
    stA(0, 0, Sa);
    BAR;
    QMFMA_H(aQ, bQ1, 4, 2, 0)
    QMFMA_H(aQ, bQ1, 4, 2, 1)
    BAR;
    // P4: MFMA A-h1 x B-h0 (4,0); VM6 validates buf1 (tile Tb); mid-reads:
    // bQ0/aQ <- buf1 h0 (for P5), in place after each k-half retires.
    stB(0, 1, Sa);
    VM6;
    BAR;
    QMFMA_H(aQ, bQ0, 4, 0, 0)
    bQ0[0] = rd8(32768 + offB[0][0]); bQ0[2] = rd8(32768 + offB[1][0]);
    aQ[0] = rd8(32768 + offA[0][0]); aQ[2] = rd8(32768 + offA[1][0]);
    aQ[4] = rd8(32768 + offA[2][0]); aQ[6] = rd8(32768 + offA[3][0]);
    QMFMA_H(aQ, bQ0, 4, 0, 1)
    bQ0[1] = rd8(32768 + offB[0][1]); bQ0[3] = rd8(32768 + offB[1][1]);
    aQ[1] = rd8(32768 + offA[0][1]); aQ[3] = rd8(32768 + offA[1][1]);
    aQ[5] = rd8(32768 + offA[2][1]); aQ[7] = rd8(32768 + offA[3][1]);
    BAR;

    // ========== tile Tb = 2it+1 (buf1) ==========
    // P5: MFMA A-h0 x B-h0; mid-reads: bQ1 <- buf1 B-h1.
    stA(0, 1, Sa);
    BAR;
    QMFMA_H(aQ, bQ0, 0, 0, 0)
    bQ1[0] = rd8(32768 + offB[2][0]); bQ1[2] = rd8(32768 + offB[3][0]);
    QMFMA_H(aQ, bQ0, 0, 0, 1)
    bQ1[1] = rd8(32768 + offB[2][1]); bQ1[3] = rd8(32768 + offB[3][1]);
    BAR;
    // P6: MFMA A-h0 x B-h1; mid-reads: aQ <- buf1 A-h1.
    stB(1, 0, Sb);
    BAR;
    QMFMA_H(aQ, bQ1, 0, 2, 0)
    aQ[0] = rd8(32768 + offA[4][0]); aQ[2] = rd8(32768 + offA[5][0]);
    aQ[4] = rd8(32768 + offA[6][0]); aQ[6] = rd8(32768 + offA[7][0]);
    QMFMA_H(aQ, bQ1, 0, 2, 1)
    aQ[1] = rd8(32768 + offA[4][1]); aQ[3] = rd8(32768 + offA[5][1]);
    aQ[5] = rd8(32768 + offA[6][1]); aQ[7] = rd8(32768 + offA[7][1]);
    BAR;
    // P7: MFMA A-h1 x B-h1; no reads.
    stA(1, 0, Sb);
    BAR;
    QMFMA_H(aQ, bQ1, 4, 2, 0)
    QMFMA_H(aQ, bQ1, 4, 2, 1)
    BAR;
    // P8: MFMA A-h1 x B-h0; VM6 validates buf0 (tile Sa); mid-reads:
    // bQ0/aQ <- buf0 h0 (for next-iter P1).
    stB(1, 1, Sb);
    VM6;
    BAR;
    QMFMA_H(aQ, bQ0, 4, 0, 0)
    bQ0[0] = rd8(offB[0][0]); bQ0[2] = rd8(offB[1][0]);
    aQ[0] = rd8(offA[0][0]); aQ[2] = rd8(offA[1][0]);
    aQ[4] = rd8(offA[2][0]); aQ[6] = rd8(offA[3][0]);
    QMFMA_H(aQ, bQ0, 4, 0, 1)
    bQ0[1] = rd8(offB[0][1]); bQ0[3] = rd8(offB[1][1]);
    aQ[1] = rd8(offA[0][1]); aQ[3] = rd8(offA[1][1]);
    aQ[5] = rd8(offA[2][1]); aQ[7] = rd8(offA[3][1]);
    BAR;
  }
  asm volatile("s_waitcnt vmcnt(0)" ::: "memory");

  // Epilogue. Interleaved mapping: row = m0 + (mi*2+wr)*16 + (l>>4)*4 + i2,
  // col = n0 + (nj*4+wc)*16 + (l&15).
  int lr4 = (l >> 4) * 4;
  int lc = l & 15;
#pragma unroll
  for (int mi = 0; mi < 8; ++mi) {
#pragma unroll
    for (int i2 = 0; i2 < 4; ++i2) {
      int rrow = (int)m0 + (mi * 2 + wr) * 16 + lr4 + i2;
      size_t base = (size_t)rrow * N;
#pragma unroll
      for (int nj = 0; nj < 4; ++nj) {
        int col = (int)n0 + (nj * 4 + wc) * 16 + lc;
        float v = acc[mi][nj][i2];
        if (EPI == 0) {
          float x = v + eb1[col];
          float u = 0.7978845608028654f * (x + 0.044715f * x * x * x);
          float th = 1.f - 2.f / (__expf(2.f * u) + 1.f);  // tanh(u)
          outb[base + col] = f2bf(0.5f * x * (1.f + th));
        } else {
          outf[base + col] =
              v + eb1[col] + eb2[col] + add1[base + col] + add2[base + col];
        }
      }
    }
  }

  // ---- post-epilogue fused-T2 tail (EPI==0): LDS transpose + bf16 store,
  // loads pipelined ONE TILE AHEAD (16-VGPR live range confined to tail).
  // One barrier/tile: W_{j+1} targets the other buffer; W_{j+2} vs R_j is
  // separated by sync_{j+1}.
  if (EPI == 0) {
    __syncthreads();  // all waves done with K-loop LDS
    float (*tl0)[65] = (float (*)[65])(void*)lds;
    float (*tl1)[65] = (float (*)[65])(void*)(lds + 16640);
    const int trr = t >> 3;        // 0..63
    const int trc = (t & 7) * 8;   // 0,8,...,56
    const size_t srcoff = (size_t)trr * H_DIM + trc;
    // preload tile 0 into the even-parity registers
    const float* s0 =
        tsrc + (size_t)(bid >> 6) * 64 * H_DIM + (bid & 63) * 64 + srcoff;
    float4 pa0 = *(const float4*)s0;
    float4 pa1 = *(const float4*)(s0 + 4);
    float4 pb0 = {0.f, 0.f, 0.f, 0.f}, pb1 = {0.f, 0.f, 0.f, 0.f};
#pragma unroll
    for (int j = 0; j < 16; ++j) {
      float (*cur)[65] = (j & 1) ? tl1 : tl0;
      float4 q0 = (j & 1) ? pb0 : pa0;
      float4 q1 = (j & 1) ? pb1 : pa1;
      cur[trr][trc + 0] = q0.x; cur[trr][trc + 1] = q0.y;
      cur[trr][trc + 2] = q0.z; cur[trr][trc + 3] = q0.w;
      cur[trr][trc + 4] = q1.x; cur[trr][trc + 5] = q1.y;
      cur[trr][trc + 6] = q1.z; cur[trr][trc + 7] = q1.w;
      if (j < 15) {  // issue next tile's loads; consumed next iteration
        int tau2 = bid + (j + 1) * 1024;
        const float* s2 =
            tsrc + (size_t)(tau2 >> 6) * 64 * H_DIM + (tau2 & 63) * 64 + srcoff;
        if (j & 1) {
          pa0 = *(const float4*)s2; pa1 = *(const float4*)(s2 + 4);
        } else {
          pb0 = *(const float4*)s2; pb1 = *(const float4*)(s2 + 4);
        }
      }
      __syncthreads();
      int tau = bid + j * 1024;
      int bk = tau >> 6, bn = tau & 63;
      u16x4 o0, o1;
      o0.x = f2bf(cur[trc + 0][trr]); o0.y = f2bf(cur[trc + 1][trr]);
      o0.z = f2bf(cur[trc + 2][trr]); o0.w = f2bf(cur[trc + 3][trr]);
      o1.x = f2bf(cur[trc + 4][trr]); o1.y = f2bf(cur[trc + 5][trr]);
      o1.z = f2bf(cur[trc + 6][trr]); o1.w = f2bf(cur[trc + 7][trr]);
      bf16_t* dst = tdst + (size_t)(bn * 64 + trr) * DFF_DIM + bk * 64 + trc;
      *(u16x4*)dst = o0;
      *(u16x4*)(dst + 4) = o1;
    }
  }
}

// ---------------------------------------------------------------------------
extern "C" void kernel_launch(void* const* d_in, const int* in_sizes, int n_in,
                              void* d_out, int out_size, void* d_ws,
                              size_t ws_size, hipStream_t stream) {
  const float* input = (const float*)d_in[0];
  const float* residual = (const float*)d_in[1];
  const float* bias = (const float*)d_in[3];
  const float* attn_nw = (const float*)d_in[4];
  const float* attn_nb = (const float*)d_in[5];
  const float* inter_w = (const float*)d_in[6];   // [H, DFF]
  const float* inter_b = (const float*)d_in[7];   // [DFF]
  const float* output_w = (const float*)d_in[8];  // [DFF, H]
  const float* output_b = (const float*)d_in[9];  // [H]
  float* out = (float*)d_out;

  char* ws = (char*)d_ws;
  bf16_t* lnb = (bf16_t*)ws;
  bf16_t* w1t = (bf16_t*)(ws + (size_t)NROWS * H_DIM * 2);
  bf16_t* w2t = (bf16_t*)(ws + (size_t)NROWS * H_DIM * 2 +
                          (size_t)H_DIM * DFF_DIM * 2);
  bf16_t* inter = (bf16_t*)(ws + (size_t)NROWS * H_DIM * 2 +
                            2 * (size_t)H_DIM * DFF_DIM * 2);

  fused_ln_kernel<<<NROWS, 256, 0, stream>>>(input, residual, bias, attn_nw,
                                             attn_nb, lnb);
  transpose_cvt_kernel<<<(H_DIM / 64) * (DFF_DIM / 64), 256, 0, stream>>>(
      inter_w, w1t, H_DIM, DFF_DIM);
  // GEMM1 with fused T2 (output_w -> w2t): pipelined LDS-transpose tail.
  gemm8p_kernel<0><<<(NROWS / 256) * (DFF_DIM / 256), 512, 0, stream>>>(
      lnb, w1t, NROWS, DFF_DIM, H_DIM, inter_b, nullptr, nullptr, nullptr,
      inter, nullptr, output_w, w2t);
  gemm8p_kernel<1><<<(NROWS / 256) * (H_DIM / 256), 512, 0, stream>>>(
      inter, w2t, NROWS, H_DIM, DFF_DIM, bias, output_b, residual, input,
      nullptr, out, nullptr, nullptr);
}